// Round 1
// baseline (420.468 us; speedup 1.0000x reference)
//
#include <hip/hip_runtime.h>
#include <math.h>

// Exact (erf-based) GELU, elementwise over 4*4096*4096 fp32.
// Memory-bound: 512 MiB mandatory HBM traffic; floor ~82 us at the
// fill-demonstrated ~6.5 TB/s streaming ceiling.
//
// This revision vs previous:
//  - grid-stride loop, 2048 blocks x 256 threads (8 blocks/CU -> full
//    32-wave occupancy), 32 iterations/thread instead of 65,536 one-shot
//    blocks (removes per-block dispatch/setup overhead).
//  - nontemporal (nt) loads/stores: zero-reuse stream, bypass L2/L3
//    allocation thrash.
//  - #pragma unroll 4: four independent global_load_dwordx4 in flight
//    per thread.

typedef __attribute__((ext_vector_type(4))) float f32x4;

__device__ __forceinline__ float gelu1(float v) {
  // exact GELU: 0.5*x*(1+erf(x/sqrt(2)))
  return 0.5f * v * (1.0f + erff(v * 0.70710678118654752440f));
}

__global__ __launch_bounds__(256) void gelu_f32x4_kernel(
    const f32x4* __restrict__ x, f32x4* __restrict__ out, int n4) {
  const int stride = gridDim.x * blockDim.x;
  int i = blockIdx.x * blockDim.x + threadIdx.x;
#pragma unroll 4
  for (; i < n4; i += stride) {
    f32x4 v = __builtin_nontemporal_load(&x[i]);
    f32x4 r;
    r.x = gelu1(v.x);
    r.y = gelu1(v.y);
    r.z = gelu1(v.z);
    r.w = gelu1(v.w);
    __builtin_nontemporal_store(r, &out[i]);
  }
}

// Tail (n not divisible by 4) — not hit for 4*4096*4096 but kept for safety.
__global__ void gelu_f32_tail_kernel(const float* __restrict__ x,
                                     float* __restrict__ out, int start, int n) {
  int i = start + blockIdx.x * blockDim.x + threadIdx.x;
  if (i >= n) return;
  float v = x[i];
  out[i] = 0.5f * v * (1.0f + erff(v * 0.70710678118654752440f));
}

extern "C" void kernel_launch(void* const* d_in, const int* in_sizes, int n_in,
                              void* d_out, int out_size, void* d_ws, size_t ws_size,
                              hipStream_t stream) {
  const float* x = (const float*)d_in[0];
  float* out = (float*)d_out;
  int n = in_sizes[0];
  int n4 = n / 4;

  if (n4 > 0) {
    const int block = 256;
    // 2048 blocks = 8 blocks/CU on 256 CUs -> max occupancy, grid-stride
    // covers the rest. Shrink for tiny inputs.
    int grid = 2048;
    long long needed = ((long long)n4 + block - 1) / block;
    if (needed < grid) grid = (int)needed;
    gelu_f32x4_kernel<<<grid, block, 0, stream>>>(
        (const f32x4*)x, (f32x4*)out, n4);
  }
  int tail_start = n4 * 4;
  int tail = n - tail_start;
  if (tail > 0) {
    gelu_f32_tail_kernel<<<1, 64, 0, stream>>>(x, out, tail_start, n);
  }
}

// Round 2
// 407.802 us; speedup vs baseline: 1.0311x; 1.0311x over previous
//
#include <hip/hip_runtime.h>
#include <math.h>

// Exact (erf-based) GELU, elementwise over 4*4096*4096 fp32.
// Memory-bound: 536.9 MB mandatory HBM traffic (256 MiB read + 256 MiB
// write); floor ~83 us at the fill-demonstrated ~6.5 TB/s streaming
// ceiling. Harness dur_us additionally contains ~330 us of 1 GiB
// re-poison fills (visible in rocprof as fillBufferAligned @ ~165 us
// each) -- unreachable from kernel code.
//
// This is the measured-best variant (409-411 us harness): one-shot
// float4 grid, 256 threads/block. Grid-stride + nontemporal (round 1)
// measured +2% -- reverted.

__global__ __launch_bounds__(256) void gelu_f32x4_kernel(
    const float4* __restrict__ x, float4* __restrict__ out, int n4) {
  int i = blockIdx.x * blockDim.x + threadIdx.x;
  if (i >= n4) return;
  float4 v = x[i];
  const float kInvSqrt2 = 0.70710678118654752440f;
  float4 r;
  r.x = 0.5f * v.x * (1.0f + erff(v.x * kInvSqrt2));
  r.y = 0.5f * v.y * (1.0f + erff(v.y * kInvSqrt2));
  r.z = 0.5f * v.z * (1.0f + erff(v.z * kInvSqrt2));
  r.w = 0.5f * v.w * (1.0f + erff(v.w * kInvSqrt2));
  out[i] = r;
}

// Tail (n not divisible by 4) -- not hit for 4*4096*4096 but kept for safety.
__global__ void gelu_f32_tail_kernel(const float* __restrict__ x,
                                     float* __restrict__ out, int start, int n) {
  int i = start + blockIdx.x * blockDim.x + threadIdx.x;
  if (i >= n) return;
  float v = x[i];
  out[i] = 0.5f * v * (1.0f + erff(v * 0.70710678118654752440f));
}

extern "C" void kernel_launch(void* const* d_in, const int* in_sizes, int n_in,
                              void* d_out, int out_size, void* d_ws, size_t ws_size,
                              hipStream_t stream) {
  const float* x = (const float*)d_in[0];
  float* out = (float*)d_out;
  int n = in_sizes[0];
  int n4 = n / 4;

  if (n4 > 0) {
    int block = 256;
    int grid = (n4 + block - 1) / block;
    gelu_f32x4_kernel<<<grid, block, 0, stream>>>((const float4*)x, (float4*)out, n4);
  }
  int tail_start = n4 * 4;
  int tail = n - tail_start;
  if (tail > 0) {
    gelu_f32_tail_kernel<<<1, 64, 0, stream>>>(x, out, tail_start, n);
  }
}